// Round 1
// baseline (4914.581 us; speedup 1.0000x reference)
//
#include <hip/hip_runtime.h>

#define Bq 64
#define Sq 32
#define VFq 512
#define IFq 256
#define Fq 768
#define Uq 768
#define UNFq 6
#define L2E 1.44269504088896340736f

// ---------------- K1: fold+transpose params, init state ----------------
// P[u][v] = float4(-sigma*log2e, sigma*mu*log2e, w, w*erev)  (u = target, v = source)
__global__ __launch_bounds__(256) void k_prep(
    const float* __restrict__ smu, const float* __restrict__ ssig,
    const float* __restrict__ sw,  const float* __restrict__ ser,
    const float* __restrict__ rmu, const float* __restrict__ rsig,
    const float* __restrict__ rw,  const float* __restrict__ rer,
    const float* __restrict__ ts,
    float4* __restrict__ Ps, float4* __restrict__ Pr,
    float* __restrict__ vg, float* __restrict__ iel, unsigned* __restrict__ ctr)
{
  int bid = blockIdx.x, tid = threadIdx.x;
  if (bid < 1152) {
    int set = bid / 576, tile = bid % 576;
    int tv = tile / 24, tu = tile % 24;
    const float* Amu = set ? rmu : smu;
    const float* Asg = set ? rsig : ssig;
    const float* Aw  = set ? rw  : sw;
    const float* Aer = set ? rer : ser;
    float4* P = set ? Pr : Ps;
    __shared__ float4 tl[32][33];
    int cu = tid & 31, r0 = tid >> 5;            // 32 cols x 8 rows
    for (int rr = 0; rr < 32; rr += 8) {
      int v = tv*32 + r0 + rr, u = tu*32 + cu;
      int idx = v*Uq + u;                         // source-major input layout
      float sg = Asg[idx], m = Amu[idx], ww = Aw[idx], er = Aer[idx];
      tl[cu][r0+rr] = make_float4(-sg*L2E, sg*m*L2E, ww, ww*er); // transposed in LDS
    }
    __syncthreads();
    for (int rr = 0; rr < 32; rr += 8) {
      int u = tu*32 + r0 + rr, v = tv*32 + (tid & 31);
      P[u*Fq + v] = tl[r0+rr][tid & 31];          // coalesced write, [u][v]
    }
  } else if (bid < 1536) {
    int i = (bid - 1152)*256 + tid;               // zero v state (2 parities), 98304
    vg[i] = 0.0f;
  } else {
    for (int i = tid; i < Bq*Sq; i += 256) {
      int b = i / Sq, t = i % Sq;
      iel[i] = (float)UNFq / (ts[b*(Sq+1)+t+1] - ts[b*(Sq+1)+t]); // 6/elapsed
    }
    if (tid < 64) ctr[tid] = 0u;                  // barrier counters
  }
}

// ---------------- K2: sensory synapse sums for all (b,t) ----------------
// block: 16 (b,t) entries x 12 target-u (one per wave) x 64 source lanes
__global__ __launch_bounds__(768) void k_sensory(
    const float* __restrict__ fv, const float* __restrict__ fi,
    const float* __restrict__ iw, const float* __restrict__ ib,
    const float4* __restrict__ Ps,
    float* __restrict__ wns, float* __restrict__ wds)
{
  __shared__ float xs[16][Fq];
  __shared__ float scr[12][8][33];
  int tid = threadIdx.x;
  int bt_tile = blockIdx.x >> 6;                  // 128 tiles of 16 (b,t)
  int ut = blockIdx.x & 63;                       // 64 u-tiles of 12
  int u0 = ut * 12, bt0 = bt_tile * 16;
  {
    float wv = iw[tid], bv = ib[tid];
    for (int j = 0; j < 16; ++j) {
      int bt = bt0 + j, b = bt >> 5, t = bt & 31;
      float raw = (tid < VFq) ? fv[(b*Sq + t)*VFq + tid]
                              : fi[(b*Sq + t)*IFq + (tid - VFq)];
      xs[j][tid] = raw * wv + bv;
    }
  }
  __syncthreads();
  int w = tid >> 6, l = tid & 63;
  const float4* P = Ps + (u0 + w)*Fq;
  float num[16], den[16];
  #pragma unroll
  for (int j = 0; j < 16; ++j) { num[j] = 0.f; den[j] = 0.f; }
  for (int i = 0; i < 12; ++i) {
    int f = l + 64*i;
    float4 p = P[f];
    #pragma unroll
    for (int j = 0; j < 16; ++j) {
      float arg = fmaf(p.x, xs[j][f], p.y);       // -sigma*(x-mu)*log2e
      float e = __builtin_amdgcn_exp2f(arg);
      float r = __builtin_amdgcn_rcpf(1.0f + e);  // sigmoid
      den[j] = fmaf(p.z, r, den[j]);
      num[j] = fmaf(p.w, r, num[j]);
    }
  }
  #pragma unroll
  for (int m = 1; m <= 4; m <<= 1) {
    #pragma unroll
    for (int j = 0; j < 16; ++j) {
      num[j] += __shfl_xor(num[j], m, 64);
      den[j] += __shfl_xor(den[j], m, 64);
    }
  }
  if ((l & 7) == 0) {
    int rep = l >> 3;
    #pragma unroll
    for (int j = 0; j < 16; ++j) { scr[w][rep][j] = num[j]; scr[w][rep][16+j] = den[j]; }
  }
  __syncthreads();
  if (tid < 192) {
    int u = tid >> 4, j = tid & 15;
    float nt = 0.f, dt = 0.f;
    #pragma unroll
    for (int rep = 0; rep < 8; ++rep) { nt += scr[u][rep][j]; dt += scr[u][rep][16+j]; }
    int bt = bt0 + j, b = bt >> 5, t = bt & 31;
    wns[(t*Bq + b)*Uq + (u0 + u)] = nt;
    wds[(t*Bq + b)*Uq + (u0 + u)] = dt;
  }
}

// ---------------- K3: recurrent unfolds (persistent, group barrier) ----------------
// 256 blocks = 4 groups(16 b each) x 64 u-tiles(12 u). Wave w <-> target u.
// Cross-block v exchange via relaxed agent atomics (device coherence point,
// no L2 writeback/inv -> params stay L2-hot). Barrier: monotonic counter/group.
__global__ __launch_bounds__(768) void k_recurrent(
    const float4* __restrict__ Pr,
    const float* __restrict__ wns, const float* __restrict__ wds,
    float* __restrict__ vg, const float* __restrict__ iel,
    unsigned* __restrict__ ctr,
    const float* __restrict__ gleak, const float* __restrict__ vleak,
    const float* __restrict__ cm, const float* __restrict__ ow,
    const float* __restrict__ ob, float* __restrict__ hout)
{
  __shared__ float vv[16][Uq];          // 48 KiB: v state for group's 16 batches
  __shared__ float scr[12][8][33];      // cross-lane reduce scratch
  __shared__ float sinv[16][Sq];
  __shared__ float sgl[12], sglvl[12], scm[12], sow[12], sob[12];
  int tid = threadIdx.x;
  int g = blockIdx.x >> 6;              // group 0..3 (b-range)
  int ut = blockIdx.x & 63;             // u-tile 0..63
  int u0 = ut*12, b0 = g*16;
  if (tid < 512) { int j = tid >> 5, t = tid & 31; sinv[j][t] = iel[(b0+j)*Sq + t]; }
  if (tid < 12) {
    float gl0 = gleak[u0+tid];
    sgl[tid] = gl0; sglvl[tid] = gl0 * vleak[u0+tid];
    scm[tid] = cm[u0+tid]; sow[tid] = ow[u0+tid]; sob[tid] = ob[u0+tid];
  }
  for (int j = 0; j < 16; ++j)          // initial state (parity 0, zeroed by K1)
    vv[j][tid] = __hip_atomic_load(&vg[(b0+j)*Uq + tid],
                                   __ATOMIC_RELAXED, __HIP_MEMORY_SCOPE_AGENT);
  __syncthreads();
  int w = tid >> 6, l = tid & 63;
  const float4* P = Pr + (u0 + w)*Uq;
  unsigned* myctr = ctr + g;
  int par = 0, phase = 0;
  for (int t = 0; t < Sq; ++t) {
    for (int k = 0; k < UNFq; ++k) {
      float num[16], den[16];
      #pragma unroll
      for (int j = 0; j < 16; ++j) { num[j] = 0.f; den[j] = 0.f; }
      for (int i = 0; i < 12; ++i) {
        int v = l + 64*i;
        float4 p = P[v];                // coalesced dwordx4, L2-resident
        #pragma unroll
        for (int j = 0; j < 16; ++j) {
          float arg = fmaf(p.x, vv[j][v], p.y);
          float e = __builtin_amdgcn_exp2f(arg);
          float r = __builtin_amdgcn_rcpf(1.0f + e);
          den[j] = fmaf(p.z, r, den[j]);
          num[j] = fmaf(p.w, r, num[j]);
        }
      }
      #pragma unroll
      for (int m = 1; m <= 4; m <<= 1) {
        #pragma unroll
        for (int j = 0; j < 16; ++j) {
          num[j] += __shfl_xor(num[j], m, 64);
          den[j] += __shfl_xor(den[j], m, 64);
        }
      }
      if ((l & 7) == 0) {
        int rep = l >> 3;
        #pragma unroll
        for (int j = 0; j < 16; ++j) { scr[w][rep][j] = num[j]; scr[w][rep][16+j] = den[j]; }
      }
      __syncthreads();
      if (tid < 192) {                  // one thread per (u,b): finish reduction + ODE step
        int u = tid >> 4, j = tid & 15;
        float nt = 0.f, dt = 0.f;
        #pragma unroll
        for (int rep = 0; rep < 8; ++rep) { nt += scr[u][rep][j]; dt += scr[u][rep][16+j]; }
        int ug = u0 + u, bg = b0 + j;
        nt += wns[(t*Bq + bg)*Uq + ug];
        dt += wds[(t*Bq + bg)*Uq + ug];
        float cmt = scm[u] * sinv[j][t];
        float vold = vv[j][ug];
        float vnew = (cmt*vold + sglvl[u] + nt)
                   * __builtin_amdgcn_rcpf(cmt + sgl[u] + dt + 1e-8f);
        __hip_atomic_store(&vg[(par^1)*Bq*Uq + bg*Uq + ug], vnew,
                           __ATOMIC_RELAXED, __HIP_MEMORY_SCOPE_AGENT);
        if (k == UNFq-1) hout[(bg*Sq + t)*Uq + ug] = fmaf(vnew, sow[u], sob[u]);
      }
      ++phase;
      if (phase < Sq*UNFq) {
        __builtin_amdgcn_s_waitcnt(0);  // drain own vmem before barrier (belt+suspenders)
        __syncthreads();                // all block's atomic stores globally ack'd
        if (tid == 0) {
          __hip_atomic_fetch_add(myctr, 1u, __ATOMIC_RELAXED, __HIP_MEMORY_SCOPE_AGENT);
          unsigned target = (unsigned)phase * 64u;
          while (__hip_atomic_load(myctr, __ATOMIC_RELAXED, __HIP_MEMORY_SCOPE_AGENT) < target)
            __builtin_amdgcn_s_sleep(1);
        }
        __syncthreads();
        par ^= 1;
        for (int j = 0; j < 16; ++j)    // reload fresh state (coherent atomic loads)
          vv[j][tid] = __hip_atomic_load(&vg[par*Bq*Uq + (b0+j)*Uq + tid],
                                         __ATOMIC_RELAXED, __HIP_MEMORY_SCOPE_AGENT);
        __syncthreads();
      }
    }
  }
}

// ---------------- K4: regressor head ----------------
__global__ __launch_bounds__(128) void k_head(
    const float* __restrict__ hseq, const float* __restrict__ W1,
    const float* __restrict__ b1, const float* __restrict__ W2,
    const float* __restrict__ b2, float* __restrict__ pose)
{
  __shared__ float h[Uq];
  __shared__ float x1[128];
  int bt = blockIdx.x, tid = threadIdx.x;
  for (int j = 0; j < 6; ++j) h[tid + 128*j] = hseq[bt*Uq + tid + 128*j];
  __syncthreads();
  float acc = b1[tid];
  for (int f = 0; f < Uq; ++f) acc = fmaf(h[f], W1[f*128 + tid], acc);
  x1[tid] = acc > 0.f ? acc : 0.1f*acc;            // LeakyReLU(0.1); h0 == 0
  __syncthreads();
  if (tid < 6) {
    float a2 = b2[tid];
    #pragma unroll
    for (int c = 0; c < 128; ++c) a2 = fmaf(x1[c], W2[c*6 + tid], a2);
    pose[bt*6 + tid] = a2;
  }
}

extern "C" void kernel_launch(void* const* d_in, const int* in_sizes, int n_in,
                              void* d_out, int out_size, void* d_ws, size_t ws_size,
                              hipStream_t stream) {
  const float* fv   = (const float*)d_in[0];
  const float* fi   = (const float*)d_in[2];
  const float* ts   = (const float*)d_in[4];
  const float* iw   = (const float*)d_in[5];
  const float* ibb  = (const float*)d_in[6];
  const float* smu  = (const float*)d_in[7];
  const float* ssig = (const float*)d_in[8];
  const float* sw   = (const float*)d_in[9];
  const float* ser  = (const float*)d_in[10];
  const float* rmu  = (const float*)d_in[11];
  const float* rsig = (const float*)d_in[12];
  const float* rw   = (const float*)d_in[13];
  const float* rer  = (const float*)d_in[14];
  const float* gl   = (const float*)d_in[15];
  const float* vl   = (const float*)d_in[16];
  const float* cm   = (const float*)d_in[17];
  const float* ow   = (const float*)d_in[18];
  const float* ob   = (const float*)d_in[19];
  const float* W1   = (const float*)d_in[20];
  const float* b1   = (const float*)d_in[21];
  const float* W2   = (const float*)d_in[22];
  const float* b2   = (const float*)d_in[23];

  float* pose = (float*)d_out;                 // (B,1,S,6) = 12288 floats
  float* hseq = (float*)d_out + Bq*Sq*6;       // (B,S,U)   = 1572864 floats

  float* ws = (float*)d_ws;
  float4* Ps = (float4*)ws;                    // 2,359,296 floats
  float4* Pr = (float4*)(ws + 2359296);        // 2,359,296
  float* wns = ws + 4718592;                   // 1,572,864
  float* wds = ws + 6291456;                   // 1,572,864
  float* vg  = ws + 7864320;                   // 98,304 (2 parities)
  float* iel = ws + 7962624;                   // 2,048
  unsigned* ctr = (unsigned*)(ws + 7964672);   // 64

  k_prep<<<1537, 256, 0, stream>>>(smu, ssig, sw, ser, rmu, rsig, rw, rer,
                                   ts, Ps, Pr, vg, iel, ctr);
  k_sensory<<<8192, 768, 0, stream>>>(fv, fi, iw, ibb, Ps, wns, wds);
  k_recurrent<<<256, 768, 0, stream>>>(Pr, wns, wds, vg, iel, ctr,
                                       gl, vl, cm, ow, ob, hseq);
  k_head<<<2048, 128, 0, stream>>>(hseq, W1, b1, W2, b2, pose);
}